// Round 5
// baseline (519.549 us; speedup 1.0000x reference)
//
#include <hip/hip_runtime.h>

// B=8, L=2048, H=1024. fp32 in/out, bf16 MFMA internally.
// Pipeline: convert -> gemm<0> (Q,K proj) -> gemm<3> (vT = Wv @ xb^T, bias-by-row)
//           -> gemm<1> (P=exp(QK^T), diag=0, fused row-sum) -> gemm<2> (out = P@V / denom)
// gemm: 256x256 tile, BK=64, 8 waves (2x4), 4 phases/K-tile.
//   ALL ds_reads issued >=1 phase before their MFMA (LDS latency hides under prev MFMA cluster).
//   MFMA order Q(0,0) Q(0,2) Q(4,0) Q(4,2); reads ph1:b23(t) ph2:aB(t) ph3:aA(t+1) ph4:b01(t+1).
//   Stage ph1:Bh0(t+1) ph2:Bh1(t+1) ph3:Ah0(t+2) ph4:Ah1(t+2); VMC 6/4/2/4 (never 0).
//   Swizzle: slot = g ^ (row&7) ^ ((row>>3)&1) -- quarter-conflict-free (16 distinct slots/quarter).

typedef unsigned short u16;
typedef __bf16 bfx8 __attribute__((ext_vector_type(8)));
typedef float f32x4 __attribute__((ext_vector_type(4)));

__device__ __forceinline__ u16 f2bf(float f) {
    unsigned int x = __float_as_uint(f);
    unsigned int r = (x + 0x7fffu + ((x >> 16) & 1u)) >> 16;  // RNE
    return (u16)r;
}
__device__ __forceinline__ float bf2f(u16 u) {
    return __uint_as_float(((unsigned int)u) << 16);
}

// ---------------- fp32 -> bf16 convert (8 elems/thread) ----------------
__global__ void f32_to_bf16(const float* __restrict__ src, u16* __restrict__ dst, int n8) {
    int i = blockIdx.x * blockDim.x + threadIdx.x;
    if (i < n8) {
        float4 a = ((const float4*)src)[i * 2];
        float4 b = ((const float4*)src)[i * 2 + 1];
        ushort4 lo; lo.x = f2bf(a.x); lo.y = f2bf(a.y); lo.z = f2bf(a.z); lo.w = f2bf(a.w);
        ushort4 hi; hi.x = f2bf(b.x); hi.y = f2bf(b.y); hi.z = f2bf(b.z); hi.w = f2bf(b.w);
        ((ushort4*)dst)[i * 2] = lo;
        ((ushort4*)dst)[i * 2 + 1] = hi;
    }
}

// ---------------- 256x256 phase-ahead NT GEMM ----------------
#define FENCE asm volatile("" ::: "memory")
#define BAR   __builtin_amdgcn_s_barrier()
#define PRIO1 __builtin_amdgcn_s_setprio(1)
#define PRIO0 __builtin_amdgcn_s_setprio(0)
#define VMC(N) asm volatile("s_waitcnt vmcnt(" #N ")" ::: "memory")

// stage one HALF tile (128 rows x 64 k bf16 = 16KB) into DST at half h (2 loads/thread)
// swizzle: global granule sg = (c&7) ^ (row&7) ^ ((row>>3)&1); LDS dest linear (c*16).
#define STAGE_HALF(DST, SRC, LD, tt, h) do{ \
    _Pragma("unroll") \
    for (int rnd = 0; rnd < 2; ++rnd) { \
        int c_ = rnd * 512 + tid; \
        int row_ = (h) * 128 + (c_ >> 3); \
        int sg_ = (c_ & 7) ^ (row_ & 7) ^ ((c_ >> 6) & 1); \
        const u16* g_ = (SRC) + (long)row_ * (LD) + (tt) * 64 + (sg_ << 3); \
        char* l_ = (char*)(DST) + (h) * 16384 + rnd * 8192 + wid * 1024; \
        __builtin_amdgcn_global_load_lds((__attribute__((address_space(1))) void*)g_, \
            (__attribute__((address_space(3))) void*)l_, 16, 0, 0); \
    } \
}while(0)

#define RD_A4(dst, SARR, mibase) do{ \
    const char* _b = (const char*)(SARR) + ((wr * 128 + (mibase) * 16 + rA) * 128); \
    dst[0][0] = *(const bfx8*)(_b + 0 * 2048 + ofk0); dst[0][1] = *(const bfx8*)(_b + 0 * 2048 + ofk1); \
    dst[1][0] = *(const bfx8*)(_b + 1 * 2048 + ofk0); dst[1][1] = *(const bfx8*)(_b + 1 * 2048 + ofk1); \
    dst[2][0] = *(const bfx8*)(_b + 2 * 2048 + ofk0); dst[2][1] = *(const bfx8*)(_b + 2 * 2048 + ofk1); \
    dst[3][0] = *(const bfx8*)(_b + 3 * 2048 + ofk0); dst[3][1] = *(const bfx8*)(_b + 3 * 2048 + ofk1); \
}while(0)

#define RD_B2(dst, SARR, nibase) do{ \
    const char* _b = (const char*)(SARR) + ((wc * 64 + (nibase) * 16 + rA) * 128); \
    dst[0][0] = *(const bfx8*)(_b + 0 * 2048 + ofk0); dst[0][1] = *(const bfx8*)(_b + 0 * 2048 + ofk1); \
    dst[1][0] = *(const bfx8*)(_b + 1 * 2048 + ofk0); dst[1][1] = *(const bfx8*)(_b + 1 * 2048 + ofk1); \
}while(0)

#define MMQ(AS, BS, M0, N0) do{ \
    _Pragma("unroll") \
    for (int ks = 0; ks < 2; ++ks) \
    _Pragma("unroll") \
    for (int mi = 0; mi < 4; ++mi) \
    _Pragma("unroll") \
    for (int ni = 0; ni < 2; ++ni) \
        acc[(M0)+mi][(N0)+ni] = __builtin_amdgcn_mfma_f32_16x16x32_bf16(AS[mi][ks], BS[ni][ks], acc[(M0)+mi][(N0)+ni], 0, 0, 0); \
}while(0)

// One K-tile tt. Reads tile tt from {SA_c,SB_c}; aA(tt+1) from SA_o; b01(tt+1) from SB_o.
// Stages B(tt+1)->SB_o (ph1,ph2), A(tt+2)->SA_c (ph3,ph4).
#define TILE(SA_c, SB_c, SA_o, SB_o, tt) do{ \
    /* ph1: RD b23(t); stage Bh0(t+1); MFMA Q(0,0){aA,b01: both read last tile} */ \
    RD_B2(b23, SB_c, 2); \
    if ((tt) + 1 < NT) STAGE_HALF(SB_o, B, ldb, (tt) + 1, 0); \
    FENCE; BAR; PRIO1; MMQ(aA, b01, 0, 0); PRIO0; VMC(6); FENCE; BAR; \
    /* ph2: RD aB(t); stage Bh1(t+1); MFMA Q(0,2){aA, b23: ph1} */ \
    RD_A4(aB, SA_c, 4); \
    if ((tt) + 1 < NT) STAGE_HALF(SB_o, B, ldb, (tt) + 1, 1); \
    FENCE; BAR; PRIO1; MMQ(aA, b23, 0, 2); PRIO0; VMC(4); FENCE; BAR; \
    /* ph3: RD aA(t+1) [A(t+1) landed per VMC(4)]; stage Ah0(t+2); MFMA Q(4,0){aB: ph2, b01} */ \
    RD_A4(aA, SA_o, 0); \
    if ((tt) + 2 < NT) STAGE_HALF(SA_c, A, lda, (tt) + 2, 0); \
    FENCE; BAR; PRIO1; MMQ(aB, b01, 4, 0); PRIO0; VMC(2); FENCE; BAR; \
    /* ph4: RD b01(t+1) [B(t+1) landed per VMC(2)]; stage Ah1(t+2); MFMA Q(4,2){aB, b23} */ \
    RD_B2(b01, SB_o, 0); \
    if ((tt) + 2 < NT) STAGE_HALF(SA_c, A, lda, (tt) + 2, 1); \
    FENCE; BAR; PRIO1; MMQ(aB, b23, 4, 2); PRIO0; VMC(4); FENCE; BAR; \
}while(0)

// MODE 0: C[16384,2048] q|k: +biasCat[col], col<1024 scaled 1/1024, bf16 -> q,k buffers.
// MODE 1: p=(row==col)?0:exp(acc); bf16 P; fused row-sum atomicAdd -> den.
// MODE 2: out = acc/den[row]; fp32.
// MODE 3: vT GEMM: C[1024,16384] = Wv @ xb^T; +bias[row]; bf16 -> vT[z][h][m].
template <int MODE>
__global__ __launch_bounds__(512, 2) void gemm(
    const u16* __restrict__ Ab, const u16* __restrict__ Bb,
    int K, int lda, int ldb,
    long strideA, long strideB,
    const float* __restrict__ bias,
    u16* __restrict__ outBf, long strideP,
    float* __restrict__ den,
    float* __restrict__ outF)
{
    __shared__ __align__(16) u16 sA0[16384];
    __shared__ __align__(16) u16 sB0[16384];
    __shared__ __align__(16) u16 sA1[16384];
    __shared__ __align__(16) u16 sB1[16384];

    const int tid  = threadIdx.x;
    const int lane = tid & 63;
    const int wid  = tid >> 6;
    const int wr = wid >> 2, wc = wid & 3;   // 2x4 wave grid; wave tile 128x64
    const int z = blockIdx.z;

    // bijective XCD swizzle over (bx,by); all grids have nwg % 8 == 0
    const int nx = gridDim.x;
    int orig = blockIdx.y * nx + blockIdx.x;
    int nwg  = nx * gridDim.y;
    int wg   = (nwg & 7) ? orig : ((orig & 7) * (nwg >> 3) + (orig >> 3));
    const int bx = wg % nx, by = wg / nx;

    const u16* A = Ab + (long)z * strideA + (long)bx * 256 * lda;
    const u16* B = Bb + (long)z * strideB + (long)by * 256 * ldb;
    const int NT = K >> 6;

    const int rA  = lane & 15;
    const int cg  = lane >> 4;
    const int swz = (rA & 7) ^ (rA >> 3);
    const int ofk0 = ((cg)     ^ swz) << 4;
    const int ofk1 = ((cg | 4) ^ swz) << 4;

    f32x4 acc[8][4] = {};
    bfx8 aA[4][2], aB[4][2], b01[2][2], b23[2][2];

    // prologue: A(0), B(0), A(1); VMC(4) => A(0),B(0) landed (A(1) flying, guarded by ph2's VMC(4))
    STAGE_HALF(sA0, A, lda, 0, 0); STAGE_HALF(sA0, A, lda, 0, 1);
    STAGE_HALF(sB0, B, ldb, 0, 0); STAGE_HALF(sB0, B, ldb, 0, 1);
    STAGE_HALF(sA1, A, lda, 1, 0); STAGE_HALF(sA1, A, lda, 1, 1);
    VMC(4);
    BAR;
    RD_A4(aA, sA0, 0);
    RD_B2(b01, sB0, 0);
    FENCE;

    for (int t = 0; t < NT; t += 2) {
        TILE(sA0, sB0, sA1, sB1, t);
        TILE(sA1, sB1, sA0, sB0, t + 1);
    }

    // epilogue: C frag row = cg*4 + r, col = rA within each 16x16
    const int r0 = bx * 256 + wr * 128 + (cg << 2);
    const int c0 = by * 256 + wc * 64 + rA;
#pragma unroll
    for (int mi = 0; mi < 8; ++mi) {
#pragma unroll
        for (int r = 0; r < 4; ++r) {
            const int grow = r0 + mi * 16 + r;
            if constexpr (MODE == 0) {
#pragma unroll
                for (int ni = 0; ni < 4; ++ni) {
                    int gcol = c0 + ni * 16;
                    float v = acc[mi][ni][r] + bias[gcol];
                    if (gcol < 1024) v *= (1.0f / 1024.0f);  // fold 1/hidden into q (exact pow2)
                    int which = gcol >> 10;
                    long dst = (long)which * (16384L * 1024) + (long)grow * 1024 + (gcol & 1023);
                    outBf[dst] = f2bf(v);
                }
            } else if constexpr (MODE == 1) {
                float s = 0.0f;
#pragma unroll
                for (int ni = 0; ni < 4; ++ni) {
                    int gcol = c0 + ni * 16;
                    float p = (grow == gcol) ? 0.0f : __expf(acc[mi][ni][r]);  // |S| small: no max-sub
                    u16 pb = f2bf(p);
                    outBf[(long)z * strideP + (long)grow * 2048 + gcol] = pb;
                    s += bf2f(pb);  // denom from the SAME rounded values used in PV
                }
                s += __shfl_xor(s, 1); s += __shfl_xor(s, 2);
                s += __shfl_xor(s, 4); s += __shfl_xor(s, 8);
                if (rA == 0) atomicAdd(&den[z * 2048 + grow], s);
            } else if constexpr (MODE == 2) {
                float d = den[z * 2048 + grow];
#pragma unroll
                for (int ni = 0; ni < 4; ++ni)
                    outF[(long)z * (2048L * 1024) + (long)grow * 1024 + (c0 + ni * 16)] = acc[mi][ni][r] / d;
            } else {  // MODE 3: vT[z'][h=grow][m], z' = gcol>>11, m = gcol&2047
                float bv = bias[grow];
#pragma unroll
                for (int ni = 0; ni < 4; ++ni) {
                    int gcol = c0 + ni * 16;
                    long dst = (long)(gcol >> 11) * (1024L * 2048) + (long)grow * 2048 + (gcol & 2047);
                    outBf[dst] = f2bf(acc[mi][ni][r] + bv);
                }
            }
        }
    }
}

extern "C" void kernel_launch(void* const* d_in, const int* in_sizes, int n_in,
                              void* d_out, int out_size, void* d_ws, size_t ws_size,
                              hipStream_t stream) {
    const float* x  = (const float*)d_in[0];
    const float* Wq = (const float*)d_in[1];
    const float* bq = (const float*)d_in[2];
    const float* Wk = (const float*)d_in[3];
    const float* bk = (const float*)d_in[4];
    const float* Wv = (const float*)d_in[5];
    const float* bv = (const float*)d_in[6];
    float* out = (float*)d_out;

    // workspace layout (bytes). xb/Wb live only until gemm<3>; Pb overlays them.
    const long XB_OFF   = 0;                          // xb: 33554432 (dead after gemm<3>)
    const long WB_OFF   = 33554432;                   // Wq|Wk|Wv bf16: 6291456 (dead after gemm<3>)
    const long PB_OFF   = 0;                          // P: 67108864 (overlays xb+Wb)
    const long BIAS_OFF = 67108864;                   // 12288 (qk bias 8K + v bias 4K)
    const long DEN_OFF  = BIAS_OFF + 16384;           // 65536
    const long QK_OFF   = DEN_OFF + 65536;            // q,k: 2 * 33554432
    const long VT_OFF   = QK_OFF + 2L * 33554432;     // vT: 33554432
    const unsigned long long NEED = (unsigned long long)(VT_OFF + 33554432);
    if (ws_size < NEED) return;

    char* ws = (char*)d_ws;
    u16*   xb      = (u16*)(ws + XB_OFF);
    u16*   Wb      = (u16*)(ws + WB_OFF);
    u16*   Pb      = (u16*)(ws + PB_OFF);
    float* biasQK  = (float*)(ws + BIAS_OFF);
    float* biasV   = (float*)(ws + BIAS_OFF + 8192);
    float* den     = (float*)(ws + DEN_OFF);
    u16*   qb      = (u16*)(ws + QK_OFF);
    u16*   kb      = qb + 16384L * 1024;
    u16*   vT      = (u16*)(ws + VT_OFF);

    f32_to_bf16<<<8192, 256, 0, stream>>>(x, xb, 2097152);
    f32_to_bf16<<<512, 256, 0, stream>>>(Wq, Wb, 131072);
    f32_to_bf16<<<512, 256, 0, stream>>>(Wk, Wb + 1048576, 131072);
    f32_to_bf16<<<512, 256, 0, stream>>>(Wv, Wb + 2097152, 131072);
    hipMemcpyAsync(biasQK,        bq, 4096, hipMemcpyDeviceToDevice, stream);
    hipMemcpyAsync(biasQK + 1024, bk, 4096, hipMemcpyDeviceToDevice, stream);
    hipMemcpyAsync(biasV,         bv, 4096, hipMemcpyDeviceToDevice, stream);
    hipMemsetAsync(den, 0, 65536, stream);  // fused row-sum accumulates into this

    // Q,K projection: [16384,1024] @ [2048,1024]^T (q pre-scaled 1/1024)
    gemm<0><<<dim3(64, 8, 1), 512, 0, stream>>>(
        xb, Wb, 1024, 1024, 1024, 0, 0, biasQK, qb, 0, nullptr, nullptr);

    // vT = Wv @ xb^T: [1024,1024] @ [16384,1024]^T -> [1024,16384] (col = z*2048+m)
    gemm<3><<<dim3(4, 64, 1), 512, 0, stream>>>(
        Wb + 2097152, xb, 1024, 1024, 1024, 0, 0, biasV, vT, 0, nullptr, nullptr);

    // P = exp(Q @ K^T), diag->0, bf16, fused row sums ; per batch 2048x2048, K=1024
    gemm<1><<<dim3(8, 8, 8), 512, 0, stream>>>(
        qb, kb, 1024, 1024, 1024, 2048L * 1024, 2048L * 1024,
        nullptr, Pb, 2048L * 2048, den, nullptr);

    // out = (P @ vT^T) / denom ; per batch 2048x1024, K=2048
    gemm<2><<<dim3(8, 4, 8), 512, 0, stream>>>(
        Pb, vT, 2048, 2048, 2048, 2048L * 2048, 1024L * 2048,
        nullptr, nullptr, 0, den, out);
}